// Round 9
// baseline (899.166 us; speedup 1.0000x reference)
//
#include <hip/hip_runtime.h>
#include <math.h>

// Problem constants (fixed by the reference)
#define NB 8
#define SEQ 2048
#define HID 64
#define HDIM 32
#define ROWS (NB * SEQ)            // 16384
#define OUT_ELEMS (ROWS * HID)     // 1048576 floats (the `out` tensor)
// QSCALE = log2(e) / sqrt(32): folds softmax scale AND exp->exp2 conversion into q.
#define QSCALE 0.25503486f

// INSTRUMENTATION: attn body runs REP times (idempotent) so the dispatch
// clears the ~160us harness-fill curtain and returns PMC counters on the
// deep-prefetch structure. Slope (marginal rep) + FETCH/WRITE totals answer:
// (a) does each rep's 268MB probs write flush (WRITE ~ 1.6GB?) -> is the
//     write floor real; (b) K/V eviction thrash (FETCH >> 8MB x reps?);
// (c) did 2-3-deep prefetch fix the cold pass. Revert REP=1 next round.
#define REP 6

typedef __attribute__((ext_vector_type(8))) short bf16x8;
typedef __attribute__((ext_vector_type(4))) float f32x4;
typedef __attribute__((ext_vector_type(4))) uint u32x4;

__device__ __forceinline__ ushort f2bf(float f) {          // f32 -> bf16 RNE
    uint u = __builtin_bit_cast(uint, f);
    u += 0x7FFFu + ((u >> 16) & 1u);
    return (ushort)(u >> 16);
}
__device__ __forceinline__ float bf2f(ushort h) {
    uint u = ((uint)h) << 16;
    return __builtin_bit_cast(float, u);
}
__device__ __forceinline__ uint cvt_pk_bf16(float lo, float hi) {  // RNE pack
    uint r;
    asm("v_cvt_pk_bf16_f32 %0, %1, %2" : "=v"(r) : "v"(lo), "v"(hi));
    return r;
}

// ---------------------------------------------------------------------------
// Kernel 1: fused QKV projection + bf16 split + V transpose.
// (round-6 version: 64-row blocks, grid 256 — best measured)
// ---------------------------------------------------------------------------
__global__ __launch_bounds__(256, 1)
void qkv_proj_kernel(const float* __restrict__ hs, const float* __restrict__ qx,
                     const float* __restrict__ Wq, const float* __restrict__ bq,
                     const float* __restrict__ Wk, const float* __restrict__ bk,
                     const float* __restrict__ Wv, const float* __restrict__ bv,
                     ushort* __restrict__ q_hi, ushort* __restrict__ q_lo,
                     ushort* __restrict__ k_hi, ushort* __restrict__ vt_hi)
{
    __shared__ __align__(16) float xq_lds[64][64];  // broadcast-read only
    __shared__ __align__(16) float xh_lds[64][64];
    __shared__ float vbuf[64][65];                  // +1 pad for transpose reads

    const int t  = threadIdx.x;
    const int r0 = blockIdx.x * 64;
    const int b  = r0 >> 11;            // 64-row block never crosses a batch

#pragma unroll
    for (int u = 0; u < 4; ++u) {
        const int idx = t + 256 * u;            // float4 index 0..1023
        const int rr = idx >> 4, kk = (idx & 15) * 4;
        *(float4*)&xq_lds[rr][kk] = *(const float4*)(qx + (size_t)(r0 + rr) * HID + kk);
        *(float4*)&xh_lds[rr][kk] = *(const float4*)(hs + (size_t)(r0 + rr) * HID + kk);
    }
    __syncthreads();

    const int c = t & 63, w = t >> 6;
    const int rw = w * 16;                        // wave's 16 rows
    const int h = c >> 5, d = c & 31;
    const size_t obase = ((size_t)((b * 2 + h) * SEQ) + (r0 & 2047) + rw) * 32 + d;

    // ---------------- phase Q (hi/lo) ----------------
    {
        float4 wr[16];
#pragma unroll
        for (int i = 0; i < 16; ++i) wr[i] = *(const float4*)(Wq + c * 64 + 4 * i);
        const float bc = bq[c];
        f32x4 acc[16];
#pragma unroll
        for (int r = 0; r < 16; ++r) acc[r] = (f32x4){0.f, 0.f, 0.f, 0.f};
#pragma unroll
        for (int k4 = 0; k4 < 16; ++k4) {
#pragma unroll
            for (int r = 0; r < 16; ++r) {
                const float4 x4 = *(const float4*)&xq_lds[rw + r][k4 * 4];  // bcast
                acc[r][0] += x4.x * wr[k4].x; acc[r][1] += x4.y * wr[k4].y;
                acc[r][2] += x4.z * wr[k4].z; acc[r][3] += x4.w * wr[k4].w;
            }
        }
#pragma unroll
        for (int r = 0; r < 16; ++r) {
            const float v = (acc[r][0] + acc[r][1] + acc[r][2] + acc[r][3] + bc) * QSCALE;
            const ushort hv = f2bf(v);
            q_hi[obase + (size_t)r * 32] = hv;
            q_lo[obase + (size_t)r * 32] = f2bf(v - bf2f(hv));
        }
    }
    // ---------------- phase K (hi only) ----------------
    {
        float4 wr[16];
#pragma unroll
        for (int i = 0; i < 16; ++i) wr[i] = *(const float4*)(Wk + c * 64 + 4 * i);
        const float bc = bk[c];
        f32x4 acc[16];
#pragma unroll
        for (int r = 0; r < 16; ++r) acc[r] = (f32x4){0.f, 0.f, 0.f, 0.f};
#pragma unroll
        for (int k4 = 0; k4 < 16; ++k4) {
#pragma unroll
            for (int r = 0; r < 16; ++r) {
                const float4 x4 = *(const float4*)&xh_lds[rw + r][k4 * 4];
                acc[r][0] += x4.x * wr[k4].x; acc[r][1] += x4.y * wr[k4].y;
                acc[r][2] += x4.z * wr[k4].z; acc[r][3] += x4.w * wr[k4].w;
            }
        }
#pragma unroll
        for (int r = 0; r < 16; ++r) {
            const float v = acc[r][0] + acc[r][1] + acc[r][2] + acc[r][3] + bc;
            k_hi[obase + (size_t)r * 32] = f2bf(v);
        }
    }
    // ---------------- phase V (hi only, transposed) ----------------
    {
        float4 wr[16];
#pragma unroll
        for (int i = 0; i < 16; ++i) wr[i] = *(const float4*)(Wv + c * 64 + 4 * i);
        const float bc = bv[c];
        f32x4 acc[16];
#pragma unroll
        for (int r = 0; r < 16; ++r) acc[r] = (f32x4){0.f, 0.f, 0.f, 0.f};
#pragma unroll
        for (int k4 = 0; k4 < 16; ++k4) {
#pragma unroll
            for (int r = 0; r < 16; ++r) {
                const float4 x4 = *(const float4*)&xq_lds[rw + r][k4 * 4];  // v uses qx!
                acc[r][0] += x4.x * wr[k4].x; acc[r][1] += x4.y * wr[k4].y;
                acc[r][2] += x4.z * wr[k4].z; acc[r][3] += x4.w * wr[k4].w;
            }
        }
#pragma unroll
        for (int r = 0; r < 16; ++r)
            vbuf[rw + r][c] = acc[r][0] + acc[r][1] + acc[r][2] + acc[r][3] + bc;
    }
    __syncthreads();

    // V transpose: lane c -> (h2,d2) column; 2 groups of 8 consecutive rows
#pragma unroll
    for (int g = 0; g < 2; ++g) {
        const int row8 = (g * 4 + w) * 8;
        bf16x8 hi8;
#pragma unroll
        for (int e = 0; e < 8; ++e) hi8[e] = (short)f2bf(vbuf[row8 + e][c]);
        const size_t vo = ((size_t)((b * 2 + h) * 32) + d) * SEQ + (r0 & 2047) + row8;
        *reinterpret_cast<bf16x8*>(vt_hi + vo) = hi8;
    }
}

// ---------------------------------------------------------------------------
// Kernel 2 (v7 + REP): fused attention, 32-row blocks, grid 1024 (4/CU),
// DEEP software pipeline: pass1 K 3-ahead (ring-4); pass2 K 2-ahead (ring-3),
// V 1-ahead (ring-2). Otherwise identical math to round-6 v5.
// ---------------------------------------------------------------------------
__global__ __launch_bounds__(256, 4)
void attn_kernel(const ushort* __restrict__ q_hi, const ushort* __restrict__ q_lo,
                 const ushort* __restrict__ k_hi, const ushort* __restrict__ vt_hi,
                 float* __restrict__ d_out)
{
    __shared__ float z_buf[4][32];
    __shared__ __align__(16) float ctx_buf[4][32][32];   // 16 KB
    __shared__ __align__(16) float pstage[4][512];       // 8 KB, wave-private

    // XCD-aware swizzle: 1024 blocks -> 128 consecutive per XCD = 2 slices
    const int bid   = blockIdx.x;
    const int swz   = (bid & 7) * 128 + (bid >> 3);
    const int slice = swz >> 6;          // 0..15 == b*2 + h
    const int qb    = swz & 63;
    const int bb = slice >> 1, hh = slice & 1;
    const int q0 = qb * 32;

    const int tid  = threadIdx.x;
    const int w    = tid >> 6, lane = tid & 63;
    const int lg   = lane >> 4, li = lane & 15;   // frag: i/j = li, k = 8*lg+e
    const int cq0  = w * 512;                     // wave's column quarter

    // A-fragments (q) for the block's 2 row-tiles
    bf16x8 aqh[2], aql[2];
#pragma unroll
    for (int rt = 0; rt < 2; ++rt) {
        const size_t qoff = ((size_t)slice * SEQ + q0 + rt * 16 + li) * 32 + lg * 8;
        aqh[rt] = *reinterpret_cast<const bf16x8*>(q_hi + qoff);
        aql[rt] = *reinterpret_cast<const bf16x8*>(q_lo + qoff);
    }

    const size_t kbase = (size_t)slice * SEQ * 32;
    const size_t vbase = (size_t)slice * 32 * SEQ;

    auto Kfrag = [&](int j16) {
        return *reinterpret_cast<const bf16x8*>(
            k_hi + kbase + (size_t)(cq0 + j16 * 16 + li) * 32 + lg * 8);
    };
    auto Vfrag = [&](int c2, int dt) {
        return *reinterpret_cast<const bf16x8*>(
            vt_hi + vbase + (size_t)(dt * 16 + li) * SEQ + cq0 + c2 * 32 + lg * 8);
    };

#pragma unroll 1
    for (int rep = 0; rep < REP; ++rep) {
    // ---------- pass 1: row sums Z (K 3-ahead, ring-4) ----------
    float zacc[8];
#pragma unroll
    for (int i = 0; i < 8; ++i) zacc[i] = 0.f;
    {
        bf16x8 kb[4];
#pragma unroll
        for (int j = 0; j < 3; ++j) kb[j] = Kfrag(j);
#pragma unroll
        for (int ct = 0; ct < 32; ++ct) {
            if (ct + 3 < 32) kb[(ct + 3) & 3] = Kfrag(ct + 3);   // issue early
            const bf16x8 bh = kb[ct & 3];
#pragma unroll
            for (int rt = 0; rt < 2; ++rt) {
                f32x4 acc = {0.f, 0.f, 0.f, 0.f};
                acc = __builtin_amdgcn_mfma_f32_16x16x32_bf16(aqh[rt], bh, acc, 0, 0, 0);
                acc = __builtin_amdgcn_mfma_f32_16x16x32_bf16(aql[rt], bh, acc, 0, 0, 0);
#pragma unroll
                for (int r = 0; r < 4; ++r)
                    zacc[rt * 4 + r] += __builtin_amdgcn_exp2f(acc[r]);
            }
        }
    }
#pragma unroll
    for (int m = 1; m < 16; m <<= 1) {
#pragma unroll
        for (int i = 0; i < 8; ++i) zacc[i] += __shfl_xor(zacc[i], m, 64);
    }
    if (li == 0) {
#pragma unroll
        for (int rt = 0; rt < 2; ++rt)
#pragma unroll
            for (int r = 0; r < 4; ++r)
                z_buf[w][rt * 16 + lg * 4 + r] = zacc[rt * 4 + r];
    }
    __syncthreads();
    float rcpz[8];
#pragma unroll
    for (int rt = 0; rt < 2; ++rt)
#pragma unroll
        for (int r = 0; r < 4; ++r) {
            const int row = rt * 16 + lg * 4 + r;
            rcpz[rt * 4 + r] = 1.0f / (z_buf[0][row] + z_buf[1][row] +
                                       z_buf[2][row] + z_buf[3][row]);
        }

    // ---------- pass 2: probs + PV (K 2-ahead ring-3, V 1-ahead ring-2) ----
    f32x4 pacc[2][2];
#pragma unroll
    for (int rt = 0; rt < 2; ++rt)
#pragma unroll
        for (int dt = 0; dt < 2; ++dt) pacc[rt][dt] = (f32x4){0.f, 0.f, 0.f, 0.f};

    float* probs = d_out + OUT_ELEMS + ((size_t)slice * SEQ + q0) * SEQ;
    float* ps = &pstage[w][0];

    bf16x8 ks[3][2], vs[2][2];
    ks[0][0] = Kfrag(0); ks[0][1] = Kfrag(1);
    ks[1][0] = Kfrag(2); ks[1][1] = Kfrag(3);
    vs[0][0] = Vfrag(0, 0); vs[0][1] = Vfrag(0, 1);

#pragma unroll
    for (int c2 = 0; c2 < 16; ++c2) {
        const int sl = c2 % 3;
        if (c2 + 2 < 16) {                        // K loads 2 iters early
            const int sn = (c2 + 2) % 3;
            ks[sn][0] = Kfrag(2 * (c2 + 2));
            ks[sn][1] = Kfrag(2 * (c2 + 2) + 1);
        }
        if (c2 + 1 < 16) {                        // V loads 1 iter early
            vs[(c2 + 1) & 1][0] = Vfrag(c2 + 1, 0);
            vs[(c2 + 1) & 1][1] = Vfrag(c2 + 1, 1);
        }

        bf16x8 ap[2];
#pragma unroll
        for (int rt = 0; rt < 2; ++rt) {
            f32x4 a0 = {0.f, 0.f, 0.f, 0.f}, a1 = {0.f, 0.f, 0.f, 0.f};
            a0 = __builtin_amdgcn_mfma_f32_16x16x32_bf16(aqh[rt], ks[sl][0], a0, 0, 0, 0);
            a0 = __builtin_amdgcn_mfma_f32_16x16x32_bf16(aql[rt], ks[sl][0], a0, 0, 0, 0);
            a1 = __builtin_amdgcn_mfma_f32_16x16x32_bf16(aqh[rt], ks[sl][1], a1, 0, 0, 0);
            a1 = __builtin_amdgcn_mfma_f32_16x16x32_bf16(aql[rt], ks[sl][1], a1, 0, 0, 0);
            // p -> swizzled LDS stage (bank-safe: 2 lanes/bank)
#pragma unroll
            for (int r = 0; r < 4; ++r) {
                const int row = lg * 4 + r;
                const float p0 = __builtin_amdgcn_exp2f(a0[r]) * rcpz[rt * 4 + r];
                const float p1 = __builtin_amdgcn_exp2f(a1[r]) * rcpz[rt * 4 + r];
                ps[row * 32 + (li ^ (lg << 3))]        = p0;   // cols [0,16)
                ps[row * 32 + ((16 + li) ^ (lg << 3))] = p1;   // cols [16,32)
            }
            // probs out: full 128-B lines, nontemporal
#pragma unroll
            for (int u = 0; u < 2; ++u) {
                const int fid = lane + 64 * u;       // 0..127 float4 cells
                const int row = fid >> 3, c4 = fid & 7;
                const int pcb = (c4 * 4) ^ (((row >> 2) & 3) << 3);
                const f32x4 pv = *reinterpret_cast<const f32x4*>(&ps[row * 32 + pcb]);
                __builtin_nontemporal_store(pv, reinterpret_cast<f32x4*>(
                    probs + (size_t)(rt * 16 + row) * SEQ + cq0 + c2 * 32 + c4 * 4));
            }
            // PV A-frag: 8 p-values (row li, k-cols lg*8..+7) -> bf16 pack
            const int abase = li * 32 + ((lg ^ ((li >> 2) & 3)) << 3);
            const f32x4 pa = *reinterpret_cast<const f32x4*>(&ps[abase]);
            const f32x4 pb = *reinterpret_cast<const f32x4*>(&ps[abase + 4]);
            u32x4 pk;
            pk[0] = cvt_pk_bf16(pa[0], pa[1]); pk[1] = cvt_pk_bf16(pa[2], pa[3]);
            pk[2] = cvt_pk_bf16(pb[0], pb[1]); pk[3] = cvt_pk_bf16(pb[2], pb[3]);
            ap[rt] = __builtin_bit_cast(bf16x8, pk);
        }
        // PV for this 32-col chunk
#pragma unroll
        for (int rt = 0; rt < 2; ++rt) {
            pacc[rt][0] = __builtin_amdgcn_mfma_f32_16x16x32_bf16(ap[rt], vs[c2 & 1][0], pacc[rt][0], 0, 0, 0);
            pacc[rt][1] = __builtin_amdgcn_mfma_f32_16x16x32_bf16(ap[rt], vs[c2 & 1][1], pacc[rt][1], 0, 0, 0);
        }
    }

    // partials -> LDS, cross-wave (col-quarter) reduce, write ctx
#pragma unroll
    for (int rt = 0; rt < 2; ++rt)
#pragma unroll
        for (int dt = 0; dt < 2; ++dt)
#pragma unroll
            for (int r = 0; r < 4; ++r)
                ctx_buf[w][rt * 16 + lg * 4 + r][dt * 16 + li] = pacc[rt][dt][r];
    __syncthreads();
    {
        const int row = tid >> 3, dq = tid & 7;      // 32 rows x 8 float4
        float4 s = *reinterpret_cast<const float4*>(&ctx_buf[0][row][dq * 4]);
#pragma unroll
        for (int ww = 1; ww < 4; ++ww) {
            const float4 c = *reinterpret_cast<const float4*>(&ctx_buf[ww][row][dq * 4]);
            s.x += c.x; s.y += c.y; s.z += c.z; s.w += c.w;
        }
        *reinterpret_cast<float4*>(
            d_out + ((size_t)bb * SEQ + q0 + row) * HID + hh * HDIM + dq * 4) = s;
    }
    __syncthreads();   // LDS fully consumed before next rep rewrites it
    }  // rep
}

// ---------------------------------------------------------------------------
// Kernel 3: output projection, in place over d_out's ctx region.
// ---------------------------------------------------------------------------
__global__ __launch_bounds__(256, 1)
void out_proj_kernel(const float* __restrict__ Wo, const float* __restrict__ bo,
                     float* __restrict__ out)
{
    const int c    = threadIdx.x & 63;
    const int rloc = threadIdx.x >> 6;

    float4 wo[16];
#pragma unroll
    for (int i = 0; i < 16; ++i) wo[i] = *(const float4*)(Wo + c * 64 + 4 * i);
    const float boc = bo[c];

    for (int rg = blockIdx.x; rg < ROWS / 4; rg += gridDim.x) {
        const int row = rg * 4 + rloc;
        const float* x = out + (size_t)row * HID;  // ctx row (wave-uniform addr)
        float a = 0.f;
#pragma unroll
        for (int i = 0; i < 16; ++i) {
            const float4 x4 = *(const float4*)(x + 4 * i);
            a += x4.x * wo[i].x + x4.y * wo[i].y + x4.z * wo[i].z + x4.w * wo[i].w;
        }
        out[(size_t)row * HID + c] = a + boc;
    }
}

// ---------------------------------------------------------------------------
extern "C" void kernel_launch(void* const* d_in, const int* in_sizes, int n_in,
                              void* d_out, int out_size, void* d_ws, size_t ws_size,
                              hipStream_t stream)
{
    const float* hs = (const float*)d_in[0];
    const float* qx = (const float*)d_in[1];
    const float* Wq = (const float*)d_in[2];
    const float* bq = (const float*)d_in[3];
    const float* Wk = (const float*)d_in[4];
    const float* bk = (const float*)d_in[5];
    const float* Wv = (const float*)d_in[6];
    const float* bv = (const float*)d_in[7];
    const float* Wo = (const float*)d_in[8];
    const float* bo = (const float*)d_in[9];
    float* out = (float*)d_out;

    // workspace: 4 bf16 arrays of 16*2048*32 = 1M elements (2 MB) each = 8 MB
    const size_t N = (size_t)16 * SEQ * 32;
    ushort* q_hi  = (ushort*)d_ws;
    ushort* q_lo  = q_hi + N;
    ushort* k_hi  = q_lo + N;
    ushort* vt_hi = k_hi + N;

    qkv_proj_kernel<<<256, 256, 0, stream>>>(hs, qx, Wq, bq, Wk, bk, Wv, bv,
                                             q_hi, q_lo, k_hi, vt_hi);
    attn_kernel<<<1024, 256, 0, stream>>>(q_hi, q_lo, k_hi, vt_hi, out);
    out_proj_kernel<<<512, 256, 0, stream>>>(Wo, bo, out);
}

// Round 10
// 104.375 us; speedup vs baseline: 8.6148x; 8.6148x over previous
//
#include <hip/hip_runtime.h>
#include <math.h>

// Problem constants (fixed by the reference)
#define NB 8
#define SEQ 2048
#define HID 64
#define HDIM 32
#define ROWS (NB * SEQ)            // 16384
#define OUT_ELEMS (ROWS * HID)     // 1048576 floats (the `out` tensor)
// QSCALE = log2(e) / sqrt(32): folds softmax scale AND exp->exp2 conversion into q.
#define QSCALE 0.25503486f

typedef __attribute__((ext_vector_type(8))) short bf16x8;
typedef __attribute__((ext_vector_type(4))) float f32x4;
typedef __attribute__((ext_vector_type(4))) uint u32x4;

__device__ __forceinline__ ushort f2bf(float f) {          // f32 -> bf16 RNE
    uint u = __builtin_bit_cast(uint, f);
    u += 0x7FFFu + ((u >> 16) & 1u);
    return (ushort)(u >> 16);
}
__device__ __forceinline__ float bf2f(ushort h) {
    uint u = ((uint)h) << 16;
    return __builtin_bit_cast(float, u);
}
__device__ __forceinline__ uint cvt_pk_bf16(float lo, float hi) {  // RNE pack
    uint r;
    asm("v_cvt_pk_bf16_f32 %0, %1, %2" : "=v"(r) : "v"(lo), "v"(hi));
    return r;
}
// async global->LDS, 16B per lane; LDS dest = wave-uniform base + lane*16
__device__ __forceinline__ void glds16(const ushort* g, ushort* l) {
    __builtin_amdgcn_global_load_lds(
        (const __attribute__((address_space(1))) uint*)(g),
        (__attribute__((address_space(3))) uint*)(l), 16, 0, 0);
}

// ---------------------------------------------------------------------------
// Kernel 1: fused QKV projection + bf16 split + V transpose (round-6 version).
// ---------------------------------------------------------------------------
__global__ __launch_bounds__(256, 1)
void qkv_proj_kernel(const float* __restrict__ hs, const float* __restrict__ qx,
                     const float* __restrict__ Wq, const float* __restrict__ bq,
                     const float* __restrict__ Wk, const float* __restrict__ bk,
                     const float* __restrict__ Wv, const float* __restrict__ bv,
                     ushort* __restrict__ q_hi, ushort* __restrict__ q_lo,
                     ushort* __restrict__ k_hi, ushort* __restrict__ vt_hi)
{
    __shared__ __align__(16) float xq_lds[64][64];
    __shared__ __align__(16) float xh_lds[64][64];
    __shared__ float vbuf[64][65];

    const int t  = threadIdx.x;
    const int r0 = blockIdx.x * 64;
    const int b  = r0 >> 11;

#pragma unroll
    for (int u = 0; u < 4; ++u) {
        const int idx = t + 256 * u;
        const int rr = idx >> 4, kk = (idx & 15) * 4;
        *(float4*)&xq_lds[rr][kk] = *(const float4*)(qx + (size_t)(r0 + rr) * HID + kk);
        *(float4*)&xh_lds[rr][kk] = *(const float4*)(hs + (size_t)(r0 + rr) * HID + kk);
    }
    __syncthreads();

    const int c = t & 63, w = t >> 6;
    const int rw = w * 16;
    const int h = c >> 5, d = c & 31;
    const size_t obase = ((size_t)((b * 2 + h) * SEQ) + (r0 & 2047) + rw) * 32 + d;

    {   // ---- Q (hi/lo) ----
        float4 wr[16];
#pragma unroll
        for (int i = 0; i < 16; ++i) wr[i] = *(const float4*)(Wq + c * 64 + 4 * i);
        const float bc = bq[c];
        f32x4 acc[16];
#pragma unroll
        for (int r = 0; r < 16; ++r) acc[r] = (f32x4){0.f, 0.f, 0.f, 0.f};
#pragma unroll
        for (int k4 = 0; k4 < 16; ++k4)
#pragma unroll
            for (int r = 0; r < 16; ++r) {
                const float4 x4 = *(const float4*)&xq_lds[rw + r][k4 * 4];
                acc[r][0] += x4.x * wr[k4].x; acc[r][1] += x4.y * wr[k4].y;
                acc[r][2] += x4.z * wr[k4].z; acc[r][3] += x4.w * wr[k4].w;
            }
#pragma unroll
        for (int r = 0; r < 16; ++r) {
            const float v = (acc[r][0] + acc[r][1] + acc[r][2] + acc[r][3] + bc) * QSCALE;
            const ushort hv = f2bf(v);
            q_hi[obase + (size_t)r * 32] = hv;
            q_lo[obase + (size_t)r * 32] = f2bf(v - bf2f(hv));
        }
    }
    {   // ---- K (hi only) ----
        float4 wr[16];
#pragma unroll
        for (int i = 0; i < 16; ++i) wr[i] = *(const float4*)(Wk + c * 64 + 4 * i);
        const float bc = bk[c];
        f32x4 acc[16];
#pragma unroll
        for (int r = 0; r < 16; ++r) acc[r] = (f32x4){0.f, 0.f, 0.f, 0.f};
#pragma unroll
        for (int k4 = 0; k4 < 16; ++k4)
#pragma unroll
            for (int r = 0; r < 16; ++r) {
                const float4 x4 = *(const float4*)&xh_lds[rw + r][k4 * 4];
                acc[r][0] += x4.x * wr[k4].x; acc[r][1] += x4.y * wr[k4].y;
                acc[r][2] += x4.z * wr[k4].z; acc[r][3] += x4.w * wr[k4].w;
            }
#pragma unroll
        for (int r = 0; r < 16; ++r) {
            const float v = acc[r][0] + acc[r][1] + acc[r][2] + acc[r][3] + bc;
            k_hi[obase + (size_t)r * 32] = f2bf(v);
        }
    }
    {   // ---- V (hi only, transposed) ----
        float4 wr[16];
#pragma unroll
        for (int i = 0; i < 16; ++i) wr[i] = *(const float4*)(Wv + c * 64 + 4 * i);
        const float bc = bv[c];
        f32x4 acc[16];
#pragma unroll
        for (int r = 0; r < 16; ++r) acc[r] = (f32x4){0.f, 0.f, 0.f, 0.f};
#pragma unroll
        for (int k4 = 0; k4 < 16; ++k4)
#pragma unroll
            for (int r = 0; r < 16; ++r) {
                const float4 x4 = *(const float4*)&xq_lds[rw + r][k4 * 4];  // v uses qx!
                acc[r][0] += x4.x * wr[k4].x; acc[r][1] += x4.y * wr[k4].y;
                acc[r][2] += x4.z * wr[k4].z; acc[r][3] += x4.w * wr[k4].w;
            }
#pragma unroll
        for (int r = 0; r < 16; ++r)
            vbuf[rw + r][c] = acc[r][0] + acc[r][1] + acc[r][2] + acc[r][3] + bc;
    }
    __syncthreads();

#pragma unroll
    for (int g = 0; g < 2; ++g) {
        const int row8 = (g * 4 + w) * 8;
        bf16x8 hi8;
#pragma unroll
        for (int e = 0; e < 8; ++e) hi8[e] = (short)f2bf(vbuf[row8 + e][c]);
        const size_t vo = ((size_t)((b * 2 + h) * 32) + d) * SEQ + (r0 & 2047) + row8;
        *reinterpret_cast<bf16x8*>(vt_hi + vo) = hi8;
    }
}

// ---------------------------------------------------------------------------
// Kernel 2 (NEW): zsum — rcpz for all rows. No write stream -> K stays L2-hot.
// 64-row blocks, 4 waves = column quarters, grid 512.
// ---------------------------------------------------------------------------
__global__ __launch_bounds__(256, 2)
void zsum_kernel(const ushort* __restrict__ q_hi, const ushort* __restrict__ q_lo,
                 const ushort* __restrict__ k_hi, float* __restrict__ rz_ws)
{
    __shared__ float z_buf[4][64];

    const int bid   = blockIdx.x;
    const int swz   = (bid & 7) * 64 + (bid >> 3);
    const int slice = swz >> 5;
    const int qb    = swz & 31;
    const int q0 = qb * 64;

    const int tid  = threadIdx.x;
    const int w    = tid >> 6, lane = tid & 63;
    const int lg   = lane >> 4, li = lane & 15;
    const int cq0  = w * 512;

    bf16x8 aqh[4], aql[4];
#pragma unroll
    for (int rt = 0; rt < 4; ++rt) {
        const size_t qoff = ((size_t)slice * SEQ + q0 + rt * 16 + li) * 32 + lg * 8;
        aqh[rt] = *(const bf16x8*)(q_hi + qoff);
        aql[rt] = *(const bf16x8*)(q_lo + qoff);
    }
    const size_t kbase = (size_t)slice * SEQ * 32;
    auto Kf = [&](int j16) {
        return *(const bf16x8*)(k_hi + kbase + (size_t)(cq0 + j16 * 16 + li) * 32 + lg * 8);
    };

    float zacc[16];
#pragma unroll
    for (int i = 0; i < 16; ++i) zacc[i] = 0.f;
    bf16x8 bh = Kf(0);
#pragma unroll 2
    for (int ct = 0; ct < 32; ++ct) {
        const bf16x8 bn = Kf(ct < 31 ? ct + 1 : 31);
#pragma unroll
        for (int rt = 0; rt < 4; ++rt) {
            f32x4 a = {0.f, 0.f, 0.f, 0.f};
            a = __builtin_amdgcn_mfma_f32_16x16x32_bf16(aqh[rt], bh, a, 0, 0, 0);
            a = __builtin_amdgcn_mfma_f32_16x16x32_bf16(aql[rt], bh, a, 0, 0, 0);
#pragma unroll
            for (int r = 0; r < 4; ++r) zacc[rt * 4 + r] += __builtin_amdgcn_exp2f(a[r]);
        }
        bh = bn;
    }
#pragma unroll
    for (int m = 1; m < 16; m <<= 1)
#pragma unroll
        for (int i = 0; i < 16; ++i) zacc[i] += __shfl_xor(zacc[i], m, 64);
    if (li == 0) {
#pragma unroll
        for (int rt = 0; rt < 4; ++rt)
#pragma unroll
            for (int r = 0; r < 4; ++r)
                z_buf[w][rt * 16 + lg * 4 + r] = zacc[rt * 4 + r];
    }
    __syncthreads();
    if (tid < 64) {
        const float z = z_buf[0][tid] + z_buf[1][tid] + z_buf[2][tid] + z_buf[3][tid];
        rz_ws[(size_t)slice * SEQ + q0 + tid] = 1.0f / z;
    }
}

// ---------------------------------------------------------------------------
// Kernel 3 (NEW): single-pass attention. 64-row blocks, 512 threads (8 waves),
// grid 512 (2 blocks/CU). Per 64-col tile: K (4KB) + V (4KB) staged via
// global_load_lds (ring-3, counted vmcnt — never drained to 0 mid-loop).
// Wave wid: rt = wid&3 (16-row tile), cs = wid>>2 (QK col-half / PV d-tile).
// QK -> p into shared pstage -> probs full-line stores + PV from pstage.
// ---------------------------------------------------------------------------
__global__ __launch_bounds__(512, 4)
void attn_kernel(const ushort* __restrict__ q_hi, const ushort* __restrict__ q_lo,
                 const ushort* __restrict__ k_hi, const ushort* __restrict__ vt_hi,
                 const float* __restrict__ rz_ws, float* __restrict__ d_out)
{
    __shared__ __align__(16) ushort kbuf[3][2048];   // [ring][col*32 + chunk*8]
    __shared__ __align__(16) ushort vbuf[3][2048];   // [ring][row*64 + chunk*8]
    __shared__ __align__(16) float  ps[64 * 68];     // p stage, padded rows

    const int bid   = blockIdx.x;
    const int swz   = (bid & 7) * 64 + (bid >> 3);   // 64 consecutive per XCD
    const int slice = swz >> 5;
    const int qb    = swz & 31;
    const int bb = slice >> 1, hh = slice & 1;
    const int q0 = qb * 64;

    const int tid  = threadIdx.x;
    const int wid  = tid >> 6, lane = tid & 63;
    const int lg   = lane >> 4, li = lane & 15;
    const int rt   = wid & 3;
    const int cs   = wid >> 2;

    const size_t qoff = ((size_t)slice * SEQ + q0 + rt * 16 + li) * 32 + lg * 8;
    const bf16x8 aqh = *(const bf16x8*)(q_hi + qoff);
    const bf16x8 aql = *(const bf16x8*)(q_lo + qoff);

    float rcpz[4];
#pragma unroll
    for (int r = 0; r < 4; ++r)
        rcpz[r] = rz_ws[(size_t)slice * SEQ + q0 + rt * 16 + lg * 4 + r];

    const ushort* kslice = k_hi + (size_t)slice * SEQ * 32;
    const ushort* vslice = vt_hi + (size_t)slice * 32 * SEQ;
    float* probs = d_out + OUT_ELEMS + ((size_t)slice * SEQ + q0) * SEQ;

    // stage tile t into ring r: waves 0-3 stage K (swizzled src), 4-7 stage V
    auto STAGE = [&](int t, int ring) {
        const int j0 = t * 64;
        if (wid < 4) {
            const int col = wid * 16 + (lane >> 2);
            const int cg  = (lane & 3) ^ ((lane >> 2) & 3);
            glds16(kslice + (size_t)(j0 + col) * 32 + cg * 8,
                   &kbuf[ring][wid * 512 + lane * 8]);
        } else {
            const int w2  = wid - 4;
            const int row = w2 * 8 + (lane >> 3);
            const int cg  = (lane & 7) ^ (row & 7);
            glds16(vslice + (size_t)row * SEQ + j0 + cg * 8,
                   &vbuf[ring][w2 * 512 + lane * 8]);
        }
    };

    STAGE(0, 0); STAGE(1, 1);

    f32x4 pacc = {0.f, 0.f, 0.f, 0.f};
    int rc = 0, rs = 2;   // compute ring, stage ring

#pragma unroll 1
    for (int t = 0; t < 32; ++t) {
        // B1: all prior-iter LDS reads retired; ring slot + pstage reusable
        asm volatile("s_waitcnt lgkmcnt(0)" ::: "memory");
        __builtin_amdgcn_s_barrier();
        __builtin_amdgcn_sched_barrier(0);
        if (t + 2 < 32) STAGE(t + 2, rs);
        // B2: tile t staged (exact per-wave newer-op counts; in-order retire;
        // per wave per iter: 1 glds + 2 probs stores)
        if (t == 0)       asm volatile("s_waitcnt vmcnt(2)" ::: "memory");
        else if (t == 1)  asm volatile("s_waitcnt vmcnt(4)" ::: "memory");
        else if (t <= 29) asm volatile("s_waitcnt vmcnt(6)" ::: "memory");
        else if (t == 30) asm volatile("s_waitcnt vmcnt(5)" ::: "memory");
        else              asm volatile("s_waitcnt vmcnt(4)" ::: "memory");
        __builtin_amdgcn_s_barrier();
        __builtin_amdgcn_sched_barrier(0);

        // ---- QK: this wave's 32-col half (2 MFMA col-tiles) ----
#pragma unroll
        for (int h2 = 0; h2 < 2; ++h2) {
            const int c16 = cs * 2 + h2;
            const bf16x8 bk = *(const bf16x8*)
                &kbuf[rc][(c16 * 16 + li) * 32 + ((lg ^ (li & 3)) * 8)];
            f32x4 a = {0.f, 0.f, 0.f, 0.f};
            a = __builtin_amdgcn_mfma_f32_16x16x32_bf16(aqh, bk, a, 0, 0, 0);
            a = __builtin_amdgcn_mfma_f32_16x16x32_bf16(aql, bk, a, 0, 0, 0);
#pragma unroll
            for (int r = 0; r < 4; ++r)
                ps[(rt * 16 + lg * 4 + r) * 68 + c16 * 16 + li] =
                    __builtin_amdgcn_exp2f(a[r]) * rcpz[r];
        }
        // B3: pstage complete across waves
        asm volatile("s_waitcnt lgkmcnt(0)" ::: "memory");
        __builtin_amdgcn_s_barrier();
        __builtin_amdgcn_sched_barrier(0);

        // ---- PV: this wave's (rt, d-tile cs) quadrant over all 64 cols ----
#pragma unroll
        for (int ch = 0; ch < 2; ++ch) {
            const int pbase = (rt * 16 + li) * 68 + ch * 32 + lg * 8;
            const f32x4 pa = *(const f32x4*)&ps[pbase];
            const f32x4 pb = *(const f32x4*)&ps[pbase + 4];
            u32x4 pk;
            pk[0] = cvt_pk_bf16(pa[0], pa[1]); pk[1] = cvt_pk_bf16(pa[2], pa[3]);
            pk[2] = cvt_pk_bf16(pb[0], pb[1]); pk[3] = cvt_pk_bf16(pb[2], pb[3]);
            const bf16x8 ap = __builtin_bit_cast(bf16x8, pk);
            const int vr = cs * 16 + li;
            const bf16x8 bv = *(const bf16x8*)
                &vbuf[rc][vr * 64 + (((ch * 4 + lg) ^ (vr & 7)) * 8)];
            pacc = __builtin_amdgcn_mfma_f32_16x16x32_bf16(ap, bv, pacc, 0, 0, 0);
        }
        // ---- probs: cooperative full-line stores of the 64x64 tile ----
#pragma unroll
        for (int u = 0; u < 2; ++u) {
            const int fid = tid + 512 * u;          // 0..1023 f32x4 cells
            const int row = fid >> 4, c4 = fid & 15;
            const f32x4 pv = *(const f32x4*)&ps[row * 68 + c4 * 4];
            *(f32x4*)(probs + (size_t)row * SEQ + t * 64 + c4 * 4) = pv;
        }

        rc = (rc == 2) ? 0 : rc + 1;
        rs = (rs == 2) ? 0 : rs + 1;
    }

    // ctx: wave's 16x16 quadrant, direct stores
#pragma unroll
    for (int r = 0; r < 4; ++r)
        d_out[((size_t)bb * SEQ + q0 + rt * 16 + lg * 4 + r) * HID
              + hh * HDIM + cs * 16 + li] = pacc[r];
}

// ---------------------------------------------------------------------------
// Kernel 4: output projection, in place over d_out's ctx region.
// ---------------------------------------------------------------------------
__global__ __launch_bounds__(256, 1)
void out_proj_kernel(const float* __restrict__ Wo, const float* __restrict__ bo,
                     float* __restrict__ out)
{
    const int c    = threadIdx.x & 63;
    const int rloc = threadIdx.x >> 6;

    float4 wo[16];
#pragma unroll
    for (int i = 0; i < 16; ++i) wo[i] = *(const float4*)(Wo + c * 64 + 4 * i);
    const float boc = bo[c];

    for (int rg = blockIdx.x; rg < ROWS / 4; rg += gridDim.x) {
        const int row = rg * 4 + rloc;
        const float* x = out + (size_t)row * HID;
        float a = 0.f;
#pragma unroll
        for (int i = 0; i < 16; ++i) {
            const float4 x4 = *(const float4*)(x + 4 * i);
            a += x4.x * wo[i].x + x4.y * wo[i].y + x4.z * wo[i].z + x4.w * wo[i].w;
        }
        out[(size_t)row * HID + c] = a + boc;
    }
}

// ---------------------------------------------------------------------------
extern "C" void kernel_launch(void* const* d_in, const int* in_sizes, int n_in,
                              void* d_out, int out_size, void* d_ws, size_t ws_size,
                              hipStream_t stream)
{
    const float* hs = (const float*)d_in[0];
    const float* qx = (const float*)d_in[1];
    const float* Wq = (const float*)d_in[2];
    const float* bq = (const float*)d_in[3];
    const float* Wk = (const float*)d_in[4];
    const float* bk = (const float*)d_in[5];
    const float* Wv = (const float*)d_in[6];
    const float* bv = (const float*)d_in[7];
    const float* Wo = (const float*)d_in[8];
    const float* bo = (const float*)d_in[9];
    float* out = (float*)d_out;

    // workspace: 4 bf16 arrays (2 MB each) + rcpz (128 KB)
    const size_t N = (size_t)16 * SEQ * 32;
    ushort* q_hi  = (ushort*)d_ws;
    ushort* q_lo  = q_hi + N;
    ushort* k_hi  = q_lo + N;
    ushort* vt_hi = k_hi + N;
    float*  rz_ws = (float*)(vt_hi + N);

    qkv_proj_kernel<<<256, 256, 0, stream>>>(hs, qx, Wq, bq, Wk, bk, Wv, bv,
                                             q_hi, q_lo, k_hi, vt_hi);
    zsum_kernel<<<512, 256, 0, stream>>>(q_hi, q_lo, k_hi, rz_ws);
    attn_kernel<<<512, 512, 0, stream>>>(q_hi, q_lo, k_hi, vt_hi, rz_ws, out);
    out_proj_kernel<<<512, 256, 0, stream>>>(Wo, bo, out);
}